// Round 1
// baseline (686.576 us; speedup 1.0000x reference)
//
#include <hip/hip_runtime.h>

#define IMG 256
#define NSPLIT 4
#define STRIPE_ROWS 4
#define STRIPES (IMG / STRIPE_ROWS)

// ---------------- Kernel 1: project vertices to NDC (u, v, z) ----------------
__global__ void k_project(const float* __restrict__ verts,
                          const float* __restrict__ Km,
                          const float* __restrict__ Rm,
                          const float* __restrict__ tm,
                          const float* __restrict__ dm,
                          float4* __restrict__ pv, int B, int V) {
    int i = blockIdx.x * blockDim.x + threadIdx.x;
    if (i >= B * V) return;
    int b = i / V;
    const float* R = Rm + b * 9;
    const float* K = Km + b * 9;
    const float* t = tm + b * 3;
    const float* d = dm + b * 5;
    float px = verts[3*i], py = verts[3*i+1], pz = verts[3*i+2];
    float x = R[0]*px + R[1]*py + R[2]*pz + t[0];
    float y = R[3]*px + R[4]*py + R[5]*pz + t[1];
    float z = R[6]*px + R[7]*py + R[8]*pz + t[2];
    float iz = 1.0f / (z + 1e-9f);
    float x_ = x * iz, y_ = y * iz;
    float k1 = d[0], k2 = d[1], p1 = d[2], p2 = d[3], k3 = d[4];
    float r2 = x_*x_ + y_*y_;
    float rad = 1.0f + k1*r2 + k2*r2*r2 + k3*r2*r2*r2;
    float xd = x_*rad + 2.0f*p1*x_*y_ + p2*(r2 + 2.0f*x_*x_);
    float yd = y_*rad + p1*(r2 + 2.0f*y_*y_) + 2.0f*p2*x_*y_;
    float u  = K[0]*xd + K[1]*yd + K[2];
    float vc = K[3]*xd + K[4]*yd + K[5];
    vc = 1024.0f - vc;
    u  = (u  - 512.0f) * (1.0f/512.0f);   // == 2*(u-512)/1024 exactly
    vc = (vc - 512.0f) * (1.0f/512.0f);
    pv[i] = make_float4(u, vc, z, 0.0f);
}

// ---------------- Kernel 2: per-face constants --------------------------------
// Layout per face (4 x float4):
//  c0 = (P0x, P0y, P1x, P1y)        edge-function gradients, scaled by sign(denom)
//  c1 = (P2x, x2,  y2,  absd)
//  c2 = (rz0', rz1', rz2', Qx)      rz_i' = 1/(z_i*absd);  Qx = d(zinv)/dx
//  c3 = (ymin, ymax, 0, 0)          conservative y bbox (invalid -> +inf/-inf)
__global__ void k_facesetup(const int* __restrict__ faces,
                            const float4* __restrict__ pv,
                            float4* __restrict__ fc, int B, int V, int F) {
    int i = blockIdx.x * blockDim.x + threadIdx.x;
    if (i >= B * F) return;
    int b = i / F;
    int i0 = faces[3*i], i1 = faces[3*i+1], i2 = faces[3*i+2];
    float4 v0 = pv[b*V + i0], v1 = pv[b*V + i1], v2 = pv[b*V + i2];
    float x0=v0.x, y0=v0.y, z0=v0.z;
    float x1=v1.x, y1=v1.y, z1=v1.z;
    float x2=v2.x, y2=v2.y, z2=v2.z;
    float denom = (y1-y2)*(x0-x2) + (x2-x1)*(y0-y2);
    bool ok = (fabsf(denom) > 1e-8f) && (z0 > 1e-8f) && (z1 > 1e-8f) && (z2 > 1e-8f);
    float4 c0, c1, c2, c3;
    if (!ok) {
        c0 = make_float4(0,0,0,0);
        c1 = make_float4(0,0,0,0);
        c2 = make_float4(0,0,0,0);
        c3 = make_float4(3e38f, -3e38f, 0, 0);   // always culled
    } else {
        float s = (denom > 0.0f) ? 1.0f : -1.0f;
        float absd = fabsf(denom);
        float P0x = s*(y1-y2), P0y = s*(x2-x1);
        float P1x = s*(y2-y0), P1y = s*(x0-x2);
        float P2x = -(P0x + P1x);
        float ia  = 1.0f / absd;
        float rz0 = ia / z0, rz1 = ia / z1, rz2 = ia / z2;
        float Qx  = P0x*rz0 + P1x*rz1 + P2x*rz2;
        float ymin = fminf(y0, fminf(y1, y2)) - 1e-4f;
        float ymax = fmaxf(y0, fmaxf(y1, y2)) + 1e-4f;
        c0 = make_float4(P0x, P0y, P1x, P1y);
        c1 = make_float4(P2x, x2, y2, absd);
        c2 = make_float4(rz0, rz1, rz2, Qx);
        c3 = make_float4(ymin, ymax, 0, 0);
    }
    fc[(size_t)i*4 + 0] = c0;
    fc[(size_t)i*4 + 1] = c1;
    fc[(size_t)i*4 + 2] = c2;
    fc[(size_t)i*4 + 3] = c3;
}

// ---------------- Kernel 3: rasterize (track max of zinv == min z) ------------
template<int NS, bool DIRECT>
__global__ __launch_bounds__(256) void k_raster(const float4* __restrict__ fc,
                                                float* __restrict__ dst,
                                                int B, int F) {
    __shared__ float4 sA[256], sB[256], sC[256];
    __shared__ int s_cnt[4];
    int bid = blockIdx.x;
    int s = bid % NS;  bid /= NS;
    int stripe = bid % STRIPES;
    int b = bid / STRIPES;
    int tid  = threadIdx.x;
    int lane = tid & 63;
    int wave = tid >> 6;          // wave == row-within-stripe
    int iy = stripe * STRIPE_ROWS + wave;
    float yp = (2.0f*iy + 1.0f - IMG) * (1.0f/IMG);
    int x0 = lane * 4;
    float xp[4];
    #pragma unroll
    for (int j = 0; j < 4; ++j) xp[j] = (2.0f*(x0+j) + 1.0f - IMG) * (1.0f/IMG);
    float ylo = (2.0f*(stripe*STRIPE_ROWS) + 1.0f - IMG) * (1.0f/IMG);
    float yhi = (2.0f*(stripe*STRIPE_ROWS + STRIPE_ROWS - 1) + 1.0f - IMG) * (1.0f/IMG);
    int f_begin = (s * F) / NS, f_end = ((s+1) * F) / NS;
    const float4* fb  = fc + (size_t)b * F * 4;
    const float2* fb2 = (const float2*)fb;
    float zm[4] = {0.0f, 0.0f, 0.0f, 0.0f};

    for (int g0 = f_begin; g0 < f_end; g0 += 256) {
        int f = g0 + tid;
        bool pass = false;
        if (f < f_end) {
            float2 mm = fb2[(size_t)f*8 + 6];   // (ymin, ymax)
            pass = !(mm.x > yhi || mm.y < ylo);
        }
        unsigned long long m = __ballot(pass);
        int prefix = __popcll(m & ((1ull << lane) - 1ull));
        if (lane == 0) s_cnt[wave] = __popcll(m);
        __syncthreads();
        int base = 0;
        #pragma unroll
        for (int w = 0; w < 4; ++w) base += (w < wave) ? s_cnt[w] : 0;
        int total = s_cnt[0] + s_cnt[1] + s_cnt[2] + s_cnt[3];
        if (pass) {
            int slot = base + prefix;
            sA[slot] = fb[(size_t)f*4 + 0];
            sB[slot] = fb[(size_t)f*4 + 1];
            sC[slot] = fb[(size_t)f*4 + 2];
        }
        __syncthreads();
        for (int i = 0; i < total; ++i) {
            float4 c0 = sA[i], c1 = sB[i], c2 = sC[i];
            float dy = yp - c1.z;                 // yp - y2
            float r0 = c0.y * dy;                 // P0y*dy
            float r1 = c0.w * dy;                 // P1y*dy
            float r2 = c1.w - r0 - r1;            // absd - r0 - r1
            float qb = fmaf(r2, c2.z, fmaf(r1, c2.y, r0 * c2.x));
            #pragma unroll
            for (int j = 0; j < 4; ++j) {
                float dx = xp[j] - c1.y;          // xp - x2
                float n0 = fmaf(c0.x, dx, r0);
                float n1 = fmaf(c0.z, dx, r1);
                float n2 = fmaf(c1.x, dx, r2);
                float zi = fmaf(c2.w, dx, qb);    // interpolated 1/z
                float mn = fminf(n0, fminf(n1, n2));
                bool okp = (mn >= 0.0f) && (zi < 10.0f);  // zp > near
                zm[j] = fmaxf(zm[j], okp ? zi : 0.0f);
            }
        }
        __syncthreads();
    }

    if (DIRECT) {
        int orow = IMG - 1 - iy;                  // zbuf[:, ::-1, :]
        size_t o = (size_t)b * (IMG*IMG) + (size_t)orow * IMG + x0;
        float4 r;
        r.x = (zm[0] > 0.01f) ? 1.0f/zm[0] : 100.0f;
        r.y = (zm[1] > 0.01f) ? 1.0f/zm[1] : 100.0f;
        r.z = (zm[2] > 0.01f) ? 1.0f/zm[2] : 100.0f;
        r.w = (zm[3] > 0.01f) ? 1.0f/zm[3] : 100.0f;
        *(float4*)(dst + o) = r;
    } else {
        size_t o = (((size_t)s * B + b) * (IMG*IMG)) + (size_t)iy * IMG + x0;
        *(float4*)(dst + o) = make_float4(zm[0], zm[1], zm[2], zm[3]);
    }
}

// ---------------- Kernel 4: reduce splits, reciprocal, row flip ---------------
__global__ void k_resolve(const float* __restrict__ zs, float* __restrict__ out, int B) {
    int i = blockIdx.x * blockDim.x + threadIdx.x;
    int n = B * IMG * IMG;
    if (i >= n) return;
    int b = i / (IMG*IMG);
    int rem = i - b * (IMG*IMG);
    int r = rem >> 8;
    int xcol = rem & 255;
    int iy = IMG - 1 - r;
    size_t basei = (size_t)b * (IMG*IMG) + (size_t)iy * IMG + xcol;
    size_t stride = (size_t)B * IMG * IMG;
    float m = zs[basei];
    #pragma unroll
    for (int sp = 1; sp < NSPLIT; ++sp) m = fmaxf(m, zs[basei + (size_t)sp * stride]);
    out[i] = (m > 0.01f) ? 1.0f / m : 100.0f;   // zp = 1/zinv, background = far
}

extern "C" void kernel_launch(void* const* d_in, const int* in_sizes, int n_in,
                              void* d_out, int out_size, void* d_ws, size_t ws_size,
                              hipStream_t stream) {
    const float* verts = (const float*)d_in[0];
    const int*   faces = (const int*)d_in[1];
    const float* Km    = (const float*)d_in[2];
    const float* Rm    = (const float*)d_in[3];
    const float* tm    = (const float*)d_in[4];
    const float* dm    = (const float*)d_in[5];
    float* out = (float*)d_out;

    int B = in_sizes[2] / 9;            // K is (B,3,3)
    int V = in_sizes[0] / (3 * B);
    int F = in_sizes[1] / (3 * B);

    char* ws = (char*)d_ws;
    size_t off_fc = (((size_t)B * V * 16) + 255) & ~(size_t)255;
    size_t off_z  = ((off_fc + (size_t)B * F * 64) + 255) & ~(size_t)255;
    size_t need   = off_z + (size_t)NSPLIT * B * IMG * IMG * 4;
    float4* pv  = (float4*)ws;
    float4* fcp = (float4*)(ws + off_fc);
    float*  zsp = (float*)(ws + off_z);

    const int thr = 256;
    k_project<<<(B*V + thr-1)/thr, thr, 0, stream>>>(verts, Km, Rm, tm, dm, pv, B, V);
    k_facesetup<<<(B*F + thr-1)/thr, thr, 0, stream>>>(faces, pv, fcp, B, V, F);
    if (ws_size >= need) {
        k_raster<NSPLIT, false><<<B*STRIPES*NSPLIT, 256, 0, stream>>>(fcp, zsp, B, F);
        k_resolve<<<(B*IMG*IMG + thr-1)/thr, thr, 0, stream>>>(zsp, out, B);
    } else {
        // ws too small for split buffers: single-pass direct write
        k_raster<1, true><<<B*STRIPES, 256, 0, stream>>>(fcp, out, B, F);
    }
}

// Round 2
// 267.469 us; speedup vs baseline: 2.5669x; 2.5669x over previous
//
#include <hip/hip_runtime.h>

#define IMG 256
#define NSPLIT 16
#define STRIPE_ROWS 4
#define STRIPES (IMG / STRIPE_ROWS)

// ---------------- Kernel 1: project vertices to NDC (u, v, z) ----------------
__global__ void k_project(const float* __restrict__ verts,
                          const float* __restrict__ Km,
                          const float* __restrict__ Rm,
                          const float* __restrict__ tm,
                          const float* __restrict__ dm,
                          float4* __restrict__ pv, int B, int V) {
    int i = blockIdx.x * blockDim.x + threadIdx.x;
    if (i >= B * V) return;
    int b = i / V;
    const float* R = Rm + b * 9;
    const float* K = Km + b * 9;
    const float* t = tm + b * 3;
    const float* d = dm + b * 5;
    float px = verts[3*i], py = verts[3*i+1], pz = verts[3*i+2];
    float x = R[0]*px + R[1]*py + R[2]*pz + t[0];
    float y = R[3]*px + R[4]*py + R[5]*pz + t[1];
    float z = R[6]*px + R[7]*py + R[8]*pz + t[2];
    float iz = 1.0f / (z + 1e-9f);
    float x_ = x * iz, y_ = y * iz;
    float k1 = d[0], k2 = d[1], p1 = d[2], p2 = d[3], k3 = d[4];
    float r2 = x_*x_ + y_*y_;
    float rad = 1.0f + k1*r2 + k2*r2*r2 + k3*r2*r2*r2;
    float xd = x_*rad + 2.0f*p1*x_*y_ + p2*(r2 + 2.0f*x_*x_);
    float yd = y_*rad + p1*(r2 + 2.0f*y_*y_) + 2.0f*p2*x_*y_;
    float u  = K[0]*xd + K[1]*yd + K[2];
    float vc = K[3]*xd + K[4]*yd + K[5];
    vc = 1024.0f - vc;
    u  = (u  - 512.0f) * (1.0f/512.0f);
    vc = (vc - 512.0f) * (1.0f/512.0f);
    pv[i] = make_float4(u, vc, z, 0.0f);
}

// ---------------- Kernel 2: per-face affine constants -------------------------
// cA = (P0x, P0y, P1x, P1y)   edge gradients, scaled by sign(denom)
// cB = (P2x, P2y, A0,  A1)    n_i(x,y) = P_ix*x + P_iy*y + A_i ; inside <=> min3 >= 0
// cC = (A2,  zix, ziy, zic)   zinv(x,y) = zix*x + ziy*y + zic
// bb = (ymin, ymax)           conservative y bbox (invalid -> +inf/-inf)
__global__ void k_facesetup(const int* __restrict__ faces,
                            const float4* __restrict__ pv,
                            float4* __restrict__ cA, float4* __restrict__ cB,
                            float4* __restrict__ cC, float2* __restrict__ bb,
                            int B, int V, int F) {
    int i = blockIdx.x * blockDim.x + threadIdx.x;
    if (i >= B * F) return;
    int b = i / F;
    int i0 = faces[3*i], i1 = faces[3*i+1], i2 = faces[3*i+2];
    float4 v0 = pv[b*V + i0], v1 = pv[b*V + i1], v2 = pv[b*V + i2];
    float x0=v0.x, y0=v0.y, z0=v0.z;
    float x1=v1.x, y1=v1.y, z1=v1.z;
    float x2=v2.x, y2=v2.y, z2=v2.z;
    float denom = (y1-y2)*(x0-x2) + (x2-x1)*(y0-y2);
    bool ok = (fabsf(denom) > 1e-8f) && (z0 > 1e-8f) && (z1 > 1e-8f) && (z2 > 1e-8f);
    if (!ok) {
        cA[i] = make_float4(0,0,0,0);
        cB[i] = make_float4(0,0,0,0);
        cC[i] = make_float4(0,0,0,0);
        bb[i] = make_float2(3e38f, -3e38f);
        return;
    }
    float s = (denom > 0.0f) ? 1.0f : -1.0f;
    float absd = fabsf(denom);
    float P0x = s*(y1-y2), P0y = s*(x2-x1);
    float P1x = s*(y2-y0), P1y = s*(x0-x2);
    float P2x = -(P0x + P1x), P2y = -(P0y + P1y);
    float A0 = -(P0x*x2 + P0y*y2);
    float A1 = -(P1x*x2 + P1y*y2);
    float A2 = absd - A0 - A1;
    float ia  = 1.0f / absd;
    float rz0 = ia / z0, rz1 = ia / z1, rz2 = ia / z2;
    float zix = P0x*rz0 + P1x*rz1 + P2x*rz2;
    float ziy = P0y*rz0 + P1y*rz1 + P2y*rz2;
    float zic = A0*rz0 + A1*rz1 + A2*rz2;
    float ymin = fminf(y0, fminf(y1, y2)) - 1e-4f;
    float ymax = fmaxf(y0, fmaxf(y1, y2)) + 1e-4f;
    cA[i] = make_float4(P0x, P0y, P1x, P1y);
    cB[i] = make_float4(P2x, P2y, A0, A1);
    cC[i] = make_float4(A2, zix, ziy, zic);
    bb[i] = make_float2(ymin, ymax);
}

// ---------------- zero-init for atomic path -----------------------------------
__global__ void k_zinit(unsigned int* __restrict__ zb, int n) {
    int i = blockIdx.x * blockDim.x + threadIdx.x;
    if (i < n) zb[i] = 0u;
}

// ---------------- Kernel 3: rasterize (track max of zinv == min z) ------------
// MODE 0: write slice buffer (per-split), resolve later
// MODE 1: atomicMax into shared z-buffer (float-as-uint, monotone for >=0)
// MODE 2: direct final write (NS must be 1)
template<int NS, int MODE>
__global__ __launch_bounds__(256) void k_raster(const float4* __restrict__ cA,
                                                const float4* __restrict__ cB,
                                                const float4* __restrict__ cC,
                                                const float2* __restrict__ bb,
                                                float* __restrict__ dst,
                                                int B, int F) {
    __shared__ float4 sA[257], sB[257], sC[257];
    __shared__ int s_cnt[4];
    int bid = blockIdx.x;
    int s = bid % NS;  bid /= NS;
    int stripe = bid % STRIPES;
    int b = bid / STRIPES;
    int tid  = threadIdx.x;
    int lane = tid & 63;
    int wave = tid >> 6;          // wave == row-within-stripe
    int iy = stripe * STRIPE_ROWS + wave;
    float yp = (2.0f*iy + 1.0f - IMG) * (1.0f/IMG);
    int x0 = lane * 4;
    float xp[4];
    #pragma unroll
    for (int j = 0; j < 4; ++j) xp[j] = (2.0f*(x0+j) + 1.0f - IMG) * (1.0f/IMG);
    float ylo = (2.0f*(stripe*STRIPE_ROWS) + 1.0f - IMG) * (1.0f/IMG);
    float yhi = (2.0f*(stripe*STRIPE_ROWS + STRIPE_ROWS - 1) + 1.0f - IMG) * (1.0f/IMG);
    int f_begin = (s * F) / NS, f_end = ((s+1) * F) / NS;
    const float4* fA = cA + (size_t)b * F;
    const float4* fB = cB + (size_t)b * F;
    const float4* fC = cC + (size_t)b * F;
    const float2* fb2 = bb + (size_t)b * F;
    float zm[4] = {0.0f, 0.0f, 0.0f, 0.0f};

    for (int g0 = f_begin; g0 < f_end; g0 += 256) {
        int f = g0 + tid;
        bool pass = false;
        if (f < f_end) {
            float2 mm = fb2[f];
            pass = !(mm.x > yhi || mm.y < ylo);
        }
        unsigned long long m = __ballot(pass);
        int prefix = __popcll(m & ((1ull << lane) - 1ull));
        if (lane == 0) s_cnt[wave] = __popcll(m);
        __syncthreads();
        int base = 0;
        #pragma unroll
        for (int w = 0; w < 4; ++w) base += (w < wave) ? s_cnt[w] : 0;
        int total = s_cnt[0] + s_cnt[1] + s_cnt[2] + s_cnt[3];
        if (pass) {
            int slot = base + prefix;
            sA[slot] = fA[f];
            sB[slot] = fB[f];
            sC[slot] = fC[f];
        }
        __syncthreads();
        if (total > 0) {
            float4 ca = sA[0], cb = sB[0], cc = sC[0];
            for (int i = 0; i < total; ++i) {
                float4 na = sA[i+1], nb = sB[i+1], nc = sC[i+1];  // prefetch (slot total = don't-care)
                float e0 = fmaf(ca.y, yp, cb.z);
                float e1 = fmaf(ca.w, yp, cb.w);
                float e2 = fmaf(cb.y, yp, cc.x);
                float zr = fmaf(cc.z, yp, cc.w);
                #pragma unroll
                for (int j = 0; j < 4; ++j) {
                    float n0 = fmaf(ca.x, xp[j], e0);
                    float n1 = fmaf(ca.z, xp[j], e1);
                    float n2 = fmaf(cb.x, xp[j], e2);
                    float zi = fmaf(cc.y, xp[j], zr);
                    float mn = fminf(fminf(n0, n1), n2);
                    mn = fminf(mn, 10.0f - zi);          // fold near-plane (zinv<10)
                    zm[j] = fmaxf(zm[j], (mn >= 0.0f) ? zi : 0.0f);
                }
                ca = na; cb = nb; cc = nc;
            }
        }
        __syncthreads();
    }

    if (MODE == 2) {
        int orow = IMG - 1 - iy;                  // zbuf[:, ::-1, :]
        size_t o = (size_t)b * (IMG*IMG) + (size_t)orow * IMG + x0;
        float4 r;
        r.x = (zm[0] > 0.01f) ? 1.0f/zm[0] : 100.0f;
        r.y = (zm[1] > 0.01f) ? 1.0f/zm[1] : 100.0f;
        r.z = (zm[2] > 0.01f) ? 1.0f/zm[2] : 100.0f;
        r.w = (zm[3] > 0.01f) ? 1.0f/zm[3] : 100.0f;
        *(float4*)(dst + o) = r;
    } else if (MODE == 1) {
        size_t o = (size_t)b * (IMG*IMG) + (size_t)iy * IMG + x0;
        unsigned int* zb = (unsigned int*)dst;
        #pragma unroll
        for (int j = 0; j < 4; ++j)
            if (zm[j] > 0.0f) atomicMax(zb + o + j, __float_as_uint(zm[j]));
    } else {
        size_t o = (((size_t)s * B + b) * (IMG*IMG)) + (size_t)iy * IMG + x0;
        *(float4*)(dst + o) = make_float4(zm[0], zm[1], zm[2], zm[3]);
    }
}

// ---------------- Kernel 4: reduce slices, reciprocal, row flip ---------------
template<int NS>
__global__ void k_resolve(const float* __restrict__ zs, float* __restrict__ out, int B) {
    int i = blockIdx.x * blockDim.x + threadIdx.x;
    int n = B * IMG * IMG;
    if (i >= n) return;
    int b = i / (IMG*IMG);
    int rem = i - b * (IMG*IMG);
    int r = rem >> 8;
    int xcol = rem & 255;
    int iy = IMG - 1 - r;
    size_t basei = (size_t)b * (IMG*IMG) + (size_t)iy * IMG + xcol;
    size_t stride = (size_t)B * IMG * IMG;
    float m = zs[basei];
    #pragma unroll
    for (int sp = 1; sp < NS; ++sp) m = fmaxf(m, zs[basei + (size_t)sp * stride]);
    out[i] = (m > 0.01f) ? 1.0f / m : 100.0f;   // zp = 1/zinv, background = far
}

extern "C" void kernel_launch(void* const* d_in, const int* in_sizes, int n_in,
                              void* d_out, int out_size, void* d_ws, size_t ws_size,
                              hipStream_t stream) {
    const float* verts = (const float*)d_in[0];
    const int*   faces = (const int*)d_in[1];
    const float* Km    = (const float*)d_in[2];
    const float* Rm    = (const float*)d_in[3];
    const float* tm    = (const float*)d_in[4];
    const float* dm    = (const float*)d_in[5];
    float* out = (float*)d_out;

    int B = in_sizes[2] / 9;            // K is (B,3,3)
    int V = in_sizes[0] / (3 * B);
    int F = in_sizes[1] / (3 * B);

    char* ws = (char*)d_ws;
    size_t al = 255;
    size_t off_cA = (((size_t)B * V * 16) + al) & ~al;
    size_t off_cB = ((off_cA + (size_t)B * F * 16) + al) & ~al;
    size_t off_cC = ((off_cB + (size_t)B * F * 16) + al) & ~al;
    size_t off_bb = ((off_cC + (size_t)B * F * 16) + al) & ~al;
    size_t off_z  = ((off_bb + (size_t)B * F * 8) + al) & ~al;
    size_t zpix   = (size_t)B * IMG * IMG;
    size_t need_slice  = off_z + (size_t)NSPLIT * zpix * 4;
    size_t need_atomic = off_z + zpix * 4;

    float4* pv  = (float4*)ws;
    float4* cAp = (float4*)(ws + off_cA);
    float4* cBp = (float4*)(ws + off_cB);
    float4* cCp = (float4*)(ws + off_cC);
    float2* bbp = (float2*)(ws + off_bb);
    float*  zsp = (float*)(ws + off_z);

    const int thr = 256;
    k_project<<<(B*V + thr-1)/thr, thr, 0, stream>>>(verts, Km, Rm, tm, dm, pv, B, V);
    k_facesetup<<<(B*F + thr-1)/thr, thr, 0, stream>>>(faces, pv, cAp, cBp, cCp, bbp, B, V, F);
    if (ws_size >= need_slice) {
        k_raster<NSPLIT, 0><<<B*STRIPES*NSPLIT, 256, 0, stream>>>(cAp, cBp, cCp, bbp, zsp, B, F);
        k_resolve<NSPLIT><<<((int)zpix + thr-1)/thr, thr, 0, stream>>>(zsp, out, B);
    } else if (ws_size >= need_atomic) {
        k_zinit<<<((int)zpix + thr-1)/thr, thr, 0, stream>>>((unsigned int*)zsp, (int)zpix);
        k_raster<NSPLIT, 1><<<B*STRIPES*NSPLIT, 256, 0, stream>>>(cAp, cBp, cCp, bbp, zsp, B, F);
        k_resolve<1><<<((int)zpix + thr-1)/thr, thr, 0, stream>>>(zsp, out, B);
    } else {
        k_raster<1, 2><<<B*STRIPES, 256, 0, stream>>>(cAp, cBp, cCp, bbp, out, B, F);
    }
}